// Round 11
// baseline (226.858 us; speedup 1.0000x reference)
//
#include <hip/hip_runtime.h>
#include <math.h>

#define NQ      16384
#define NKV     32768
#define CIN     64
#define NF      128
#define NOFF    27
#define BATCH   8
#define SQ      2048
#define SKV     4096
#define BN_EPS  1e-4f
#define SPLIT   4
#define KV_PER_SPLIT (SKV / SPLIT)           // 1024
#define TILES_PER_SPLIT (KV_PER_SPLIT / 64)  // 16
#define LOG2E   1.4426950408889634f
#define SHIFT2  57.70780163555854f           // 40 * log2(e)

typedef unsigned short u16;
typedef unsigned int   u32;
typedef __attribute__((ext_vector_type(4))) float f32x4;
typedef __attribute__((ext_vector_type(8))) short s16x8;

__device__ __forceinline__ u16 f2b(float x) {
    union { float f; unsigned u; } c; c.f = x;
    unsigned r = (c.u + 0x7FFFu + ((c.u >> 16) & 1u)) >> 16;
    return (u16)r;
}
__device__ __forceinline__ float b2f(u16 x) {
    union { unsigned u; float f; } c; c.u = ((unsigned)x) << 16;
    return c.f;
}
__device__ __forceinline__ u32 pk2bf(float lo, float hi) {
    union { float f; u32 u; } a, b;
    a.f = lo; b.f = hi;
    return __builtin_amdgcn_perm(b.u + 0x8000u, a.u + 0x8000u, 0x07060302u);
}
__device__ __forceinline__ void g2l16(const void* gp, void* lp) {
    __builtin_amdgcn_global_load_lds(
        (const __attribute__((address_space(1))) unsigned*)gp,
        (__attribute__((address_space(3))) unsigned*)lp, 16, 0, 0);
}

// ---------------------------------------------------------------------------
// Kernel 1 (prep): unchanged from R9.
// ---------------------------------------------------------------------------
__device__ __forceinline__ void wtrans_one(
    const float* __restrict__ src, u16* __restrict__ dst, int K, int id, float sc)
{
    int n  = id / (K / 4);
    int k4 = (id % (K / 4)) * 4;
    const float* s = src + (size_t)k4 * NF + n;
    ushort4 o;
    o.x = f2b(s[0] * sc); o.y = f2b(s[NF] * sc);
    o.z = f2b(s[2 * NF] * sc); o.w = f2b(s[3 * NF] * sc);
    *(ushort4*)(dst + (size_t)n * K + k4) = o;
}

__global__ __launch_bounds__(256) void prep_kernel(
    const float* __restrict__ xdec_feat, const float* __restrict__ Wp1,
    const float* __restrict__ Wq, const float* __restrict__ Wk,
    const float* __restrict__ Wv, const float* __restrict__ Wt,
    u16* __restrict__ xf_bf, u16* __restrict__ wp1t,
    u16* __restrict__ wqT, u16* __restrict__ wkT,
    u16* __restrict__ wvT, u16* __restrict__ wtT,
    float* __restrict__ stats)
{
    int bid = blockIdx.x;
    int t   = threadIdx.x;
    if (bid < 1024) {
        int i = (bid * 256 + t) * 4;
        float4 v = *(const float4*)(xdec_feat + i);
        ushort4 o;
        o.x = f2b(v.x); o.y = f2b(v.y); o.z = f2b(v.z); o.w = f2b(v.w);
        *(ushort4*)(xf_bf + i) = o;
    } else if (bid < 1240) {
        int id = (bid - 1024) * 256 + t;
        int ko = id >> 11;
        int r  = id & 2047;
        int f  = r >> 4;
        int c4 = (r & 15) * 4;
        const float* s = Wp1 + (size_t)ko * 8192 + (size_t)c4 * NF + f;
        ushort4 o;
        o.x = f2b(s[0]); o.y = f2b(s[NF]); o.z = f2b(s[2 * NF]); o.w = f2b(s[3 * NF]);
        *(ushort4*)(wp1t + (size_t)ko * 8192 + (size_t)f * 64 + c4) = o;
    } else if (bid < 1288) {
        int id = (bid - 1240) * 256 + t;
        if (id < 4096)        wtrans_one(Wq, wqT, 128, id, LOG2E);
        else if (id < 6144)   wtrans_one(Wk, wkT, 64, id - 4096, 1.f);
        else if (id < 8192)   wtrans_one(Wv, wvT, 64, id - 6144, 1.f);
        else                  wtrans_one(Wt, wtT, 128, id - 8192, 1.f);
    } else {
        stats[t] = 0.f;
    }
}

// ---------------------------------------------------------------------------
// Kernel 2 (main_fused):
//  blocks [0,512): KV GEMM; V^T through a 16KB LDS tile, written out as
//                  coalesced 16B chunks (BUGFIX vs R10: uint4, full coverage).
//  blocks [512,768): p1conv MFMA (dbuf B staging) + fused q-GEMM.
// ---------------------------------------------------------------------------
__global__ __launch_bounds__(256) void main_fused_kernel(
    const float* __restrict__ xenc, const u16* __restrict__ xf,
    const int* __restrict__ nbr, const u16* __restrict__ wp1t,
    const u16* __restrict__ wqT, const u16* __restrict__ wkT,
    const u16* __restrict__ wvT,
    u16* __restrict__ kbuf, u16* __restrict__ vt,
    float* __restrict__ xdec, u16* __restrict__ qbuf)
{
    __shared__ u16 smem[2][128][64];   // p1conv B dbuf / KV-half V^T tile
    __shared__ int nbr_s[64][28];

    const int t    = threadIdx.x;
    const int w    = t >> 6;
    const int lane = t & 63;
    const int quad = lane >> 4;
    const int l15  = lane & 15;

    if (blockIdx.x < 512) {
        // ---------------- KV GEMM ----------------
        const int bm0 = blockIdx.x * 64;
        const int m0  = bm0 + w * 16;
        const float* Ap = xenc + (size_t)(m0 + l15) * CIN + quad * 8;
        float4 a0 = *(const float4*)(Ap);
        float4 a1 = *(const float4*)(Ap + 4);
        float4 a2 = *(const float4*)(Ap + 32);
        float4 a3 = *(const float4*)(Ap + 36);
        union { u16 a[8]; s16x8 v; } p0, p1;
        p0.a[0] = f2b(a0.x); p0.a[1] = f2b(a0.y); p0.a[2] = f2b(a0.z); p0.a[3] = f2b(a0.w);
        p0.a[4] = f2b(a1.x); p0.a[5] = f2b(a1.y); p0.a[6] = f2b(a1.z); p0.a[7] = f2b(a1.w);
        p1.a[0] = f2b(a2.x); p1.a[1] = f2b(a2.y); p1.a[2] = f2b(a2.z); p1.a[3] = f2b(a2.w);
        p1.a[4] = f2b(a3.x); p1.a[5] = f2b(a3.y); p1.a[6] = f2b(a3.z); p1.a[7] = f2b(a3.w);
        s16x8 af0 = p0.v, af1 = p1.v;

        u16* vtile = &smem[0][0][0];   // [128][64] view, 16 KB
        #pragma unroll
        for (int nt = 0; nt < 8; nt++) {
            f32x4 ka = (f32x4)0.f, va = (f32x4)0.f;
            const u16* Kp = wkT + (size_t)(nt * 16 + l15) * CIN + quad * 8;
            const u16* Vp = wvT + (size_t)(nt * 16 + l15) * CIN + quad * 8;
            s16x8 kb0 = *(const s16x8*)(Kp);
            s16x8 kb1 = *(const s16x8*)(Kp + 32);
            s16x8 vb0 = *(const s16x8*)(Vp);
            s16x8 vb1 = *(const s16x8*)(Vp + 32);
            ka = __builtin_amdgcn_mfma_f32_16x16x32_bf16(af0, kb0, ka, 0, 0, 0);
            ka = __builtin_amdgcn_mfma_f32_16x16x32_bf16(af1, kb1, ka, 0, 0, 0);
            va = __builtin_amdgcn_mfma_f32_16x16x32_bf16(af0, vb0, va, 0, 0, 0);
            va = __builtin_amdgcn_mfma_f32_16x16x32_bf16(af1, vb1, va, 0, 0, 0);
            #pragma unroll
            for (int r = 0; r < 4; r++)
                kbuf[(size_t)(m0 + quad * 4 + r) * NF + nt * 16 + l15] = f2b(ka[r]);
            // V^T into LDS tile: row f = nt*16+l15, kv_local = w*16+quad*4+r
            ushort4 pk;
            pk.x = f2b(va[0]); pk.y = f2b(va[1]); pk.z = f2b(va[2]); pk.w = f2b(va[3]);
            *(ushort4*)&vtile[(nt * 16 + l15) * 64 + w * 16 + quad * 4] = pk;
        }
        __syncthreads();
        // coalesced writeout: 128 f-rows x 8 chunks x 16B  (uint4 = 8 u16)
        int bb  = bm0 >> 12;
        int kv0 = bm0 & 4095;
        #pragma unroll
        for (int it = 0; it < 4; it++) {
            int idx = it * 256 + t;          // [0,1024)
            int row = idx >> 3;              // f-row 0..127
            int ch  = idx & 7;               // 16B-chunk: 8 u16
            *(uint4*)(vt + (size_t)(bb * NF + row) * SKV + kv0 + ch * 8) =
                *(const uint4*)&vtile[row * 64 + ch * 8];
        }
        return;
    }

    // ---------------- p1conv + q (unchanged from R9) ----------------
    const int base = (blockIdx.x - 512) * 64;

    for (int i = t; i < 64 * NOFF; i += 256)
        nbr_s[i / NOFF][i % NOFF] = nbr[(size_t)base * NOFF + i];

    f32x4 oacc[8];
    #pragma unroll
    for (int n = 0; n < 8; n++) oacc[n] = (f32x4)0.f;

    const int arow = w * 16 + l15;
    const int sr   = w * 32 + (lane >> 3);

    #pragma unroll
    for (int c = 0; c < 4; c++) {
        int row = sr + c * 8;
        int kk  = (lane & 7) ^ (row & 7);
        g2l16(wp1t + (size_t)row * 64 + kk * 8, &smem[0][w * 32 + c * 8][0]);
    }
    __syncthreads();

    for (int ko = 0; ko < NOFF; ko++) {
        int cur = ko & 1;
        if (ko + 1 < NOFF) {
            int nxt = (ko + 1) & 1;
            #pragma unroll
            for (int c = 0; c < 4; c++) {
                int row = sr + c * 8;
                int kk  = (lane & 7) ^ (row & 7);
                g2l16(wp1t + (size_t)(ko + 1) * 8192 + (size_t)row * 64 + kk * 8,
                      &smem[nxt][w * 32 + c * 8][0]);
            }
        }
        int nb = nbr_s[arow][ko];
        const u16* ap = xf + (size_t)nb * CIN + quad * 8;
        s16x8 af0 = *(const s16x8*)(ap);
        s16x8 af1 = *(const s16x8*)(ap + 32);
        #pragma unroll
        for (int nt = 0; nt < 8; nt++) {
            int pc0 = quad ^ (l15 & 7);
            int pc1 = (4 + quad) ^ (l15 & 7);
            s16x8 bf0 = *(const s16x8*)&smem[cur][nt * 16 + l15][pc0 * 8];
            s16x8 bf1 = *(const s16x8*)&smem[cur][nt * 16 + l15][pc1 * 8];
            oacc[nt] = __builtin_amdgcn_mfma_f32_16x16x32_bf16(af0, bf0, oacc[nt], 0, 0, 0);
            oacc[nt] = __builtin_amdgcn_mfma_f32_16x16x32_bf16(af1, bf1, oacc[nt], 0, 0, 0);
        }
        __syncthreads();
    }

    u16* xq = &smem[0][0][0];   // [64][136] view
    #pragma unroll
    for (int nt = 0; nt < 8; nt++)
        #pragma unroll
        for (int r = 0; r < 4; r++) {
            int row = w * 16 + quad * 4 + r;
            int col = nt * 16 + l15;
            xdec[(size_t)(base + row) * NF + col] = oacc[nt][r];
            xq[row * 136 + col] = f2b(oacc[nt][r]);
        }

    s16x8 aq[4];
    #pragma unroll
    for (int ks = 0; ks < 4; ks++)
        aq[ks] = *(const s16x8*)&xq[(w * 16 + l15) * 136 + ks * 32 + quad * 8];

    #pragma unroll
    for (int nt = 0; nt < 8; nt++) {
        f32x4 acc = (f32x4)0.f;
        const u16* Wp = wqT + (size_t)(nt * 16 + l15) * NF + quad * 8;
        #pragma unroll
        for (int ks = 0; ks < 4; ks++) {
            s16x8 bf = *(const s16x8*)(Wp + ks * 32);
            acc = __builtin_amdgcn_mfma_f32_16x16x32_bf16(aq[ks], bf, acc, 0, 0, 0);
        }
        #pragma unroll
        for (int r = 0; r < 4; r++)
            qbuf[(size_t)(base + w * 16 + quad * 4 + r) * NF + nt * 16 + l15] = f2b(acc[r]);
    }
}

// ---------------------------------------------------------------------------
// Kernel 3: MFMA flash attention. K fragments direct from global (L2-served);
// V^T double-buffered in LDS. 128 q/block, static-max exp2 softmax.
// grid = (SQ/128, BATCH, SPLIT) = 512 blocks, LDS 41KB.
// ---------------------------------------------------------------------------
__global__ __launch_bounds__(256) void attn_mfma_kernel(
    const u16* __restrict__ Q, const u16* __restrict__ K,
    const u16* __restrict__ Vt, u16* __restrict__ Opart,
    float* __restrict__ lpart)
{
    __shared__ u16 Vs[2][128][64];  // [buf][f][kv] phys chunk = k8 ^ (row&7)
    __shared__ u16 Ps[4][16][72];

    const int t    = threadIdx.x;
    const int b    = blockIdx.y;
    const int q0   = blockIdx.x * 128;
    const int sp   = blockIdx.z;
    const int w    = t >> 6;
    const int lane = t & 63;
    const int quad = lane >> 4;
    const int l15  = lane & 15;

    const u16* Kb  = K  + (size_t)b * SKV * NF;
    const u16* Vtb = Vt + (size_t)b * NF * SKV;

    s16x8 qf[2][4];
    #pragma unroll
    for (int g = 0; g < 2; g++) {
        const u16* Qp = Q + ((size_t)(b * SQ + q0 + w * 32 + g * 16 + l15)) * NF + quad * 8;
        #pragma unroll
        for (int ks = 0; ks < 4; ks++) qf[g][ks] = *(const s16x8*)(Qp + ks * 32);
    }

    f32x4 oacc[2][8];
    #pragma unroll
    for (int g = 0; g < 2; g++)
        #pragma unroll
        for (int n = 0; n < 8; n++) oacc[g][n] = (f32x4)0.f;
    float lrow[2] = {0.f, 0.f};

    const int kvbase = sp * KV_PER_SPLIT;
    const int vrow = w * 32 + (lane >> 3);

    // prologue: stage V tile 0 into buf 0
    #pragma unroll
    for (int c = 0; c < 4; c++) {
        int row = vrow + c * 8;
        int k8  = (lane & 7) ^ (row & 7);
        g2l16(Vtb + (size_t)row * SKV + kvbase + k8 * 8, &Vs[0][w * 32 + c * 8][0]);
    }

    for (int tile = 0; tile < TILES_PER_SPLIT; tile++) {
        const int cur = tile & 1;
        const int kv0 = kvbase + tile * 64;
        __syncthreads();   // drains staging of Vs[cur]
        if (tile + 1 < TILES_PER_SPLIT) {
            const int nxt = (tile + 1) & 1;
            int kvn = kv0 + 64;
            #pragma unroll
            for (int c = 0; c < 4; c++) {
                int row = vrow + c * 8;
                int k8  = (lane & 7) ^ (row & 7);
                g2l16(Vtb + (size_t)row * SKV + kvn + k8 * 8, &Vs[nxt][w * 32 + c * 8][0]);
            }
        }

        // S^T: K fragments straight from global (L2); shared across both q-groups
        f32x4 sacc[2][4];
        #pragma unroll
        for (int c = 0; c < 4; c++) {
            const u16* Krow = Kb + (size_t)(kv0 + c * 16 + l15) * NF + quad * 8;
            s16x8 ka0 = *(const s16x8*)(Krow);
            s16x8 ka1 = *(const s16x8*)(Krow + 32);
            s16x8 ka2 = *(const s16x8*)(Krow + 64);
            s16x8 ka3 = *(const s16x8*)(Krow + 96);
            f32x4 s0 = (f32x4)0.f, s1 = (f32x4)0.f;
            s0 = __builtin_amdgcn_mfma_f32_16x16x32_bf16(ka0, qf[0][0], s0, 0, 0, 0);
            s0 = __builtin_amdgcn_mfma_f32_16x16x32_bf16(ka1, qf[0][1], s0, 0, 0, 0);
            s0 = __builtin_amdgcn_mfma_f32_16x16x32_bf16(ka2, qf[0][2], s0, 0, 0, 0);
            s0 = __builtin_amdgcn_mfma_f32_16x16x32_bf16(ka3, qf[0][3], s0, 0, 0, 0);
            s1 = __builtin_amdgcn_mfma_f32_16x16x32_bf16(ka0, qf[1][0], s1, 0, 0, 0);
            s1 = __builtin_amdgcn_mfma_f32_16x16x32_bf16(ka1, qf[1][1], s1, 0, 0, 0);
            s1 = __builtin_amdgcn_mfma_f32_16x16x32_bf16(ka2, qf[1][2], s1, 0, 0, 0);
            s1 = __builtin_amdgcn_mfma_f32_16x16x32_bf16(ka3, qf[1][3], s1, 0, 0, 0);
            sacc[0][c] = s0;
            sacc[1][c] = s1;
        }

        // softmax per group; P through wave-private Ps; fragments kept in regs
        s16x8 pb[2][2];
        #pragma unroll
        for (int g = 0; g < 2; g++) {
            float rs = 0.f;
            float pv[4][4];
            #pragma unroll
            for (int c = 0; c < 4; c++)
                #pragma unroll
                for (int r = 0; r < 4; r++) {
                    float p = exp2f(sacc[g][c][r] - SHIFT2);
                    pv[c][r] = p;
                    rs += p;
                }
            rs += __shfl_xor(rs, 16);
            rs += __shfl_xor(rs, 32);
            lrow[g] += rs;
            #pragma unroll
            for (int c = 0; c < 4; c++) {
                uint2 pk;
                pk.x = pk2bf(pv[c][0], pv[c][1]);
                pk.y = pk2bf(pv[c][2], pv[c][3]);
                *(uint2*)&Ps[w][l15][c * 16 + quad * 4] = pk;
            }
            pb[g][0] = *(const s16x8*)&Ps[w][l15][quad * 8];
            pb[g][1] = *(const s16x8*)&Ps[w][l15][32 + quad * 8];
        }

        // joint PV from Vs[cur]
        #pragma unroll
        for (int mt = 0; mt < 8; mt++) {
            int p0 = quad ^ (l15 & 7);
            int p1 = (4 + quad) ^ (l15 & 7);
            s16x8 va0 = *(const s16x8*)&Vs[cur][mt * 16 + l15][p0 * 8];
            s16x8 va1 = *(const s16x8*)&Vs[cur][mt * 16 + l15][p1 * 8];
            oacc[0][mt] = __builtin_amdgcn_mfma_f32_16x16x32_bf16(va0, pb[0][0], oacc[0][mt], 0, 0, 0);
            oacc[0][mt] = __builtin_amdgcn_mfma_f32_16x16x32_bf16(va1, pb[0][1], oacc[0][mt], 0, 0, 0);
            oacc[1][mt] = __builtin_amdgcn_mfma_f32_16x16x32_bf16(va0, pb[1][0], oacc[1][mt], 0, 0, 0);
            oacc[1][mt] = __builtin_amdgcn_mfma_f32_16x16x32_bf16(va1, pb[1][1], oacc[1][mt], 0, 0, 0);
        }
    }

    #pragma unroll
    for (int g = 0; g < 2; g++) {
        int grow = b * SQ + q0 + w * 32 + g * 16 + l15;
        u16* Ob = Opart + (size_t)sp * NQ * NF + (size_t)grow * NF;
        #pragma unroll
        for (int mt = 0; mt < 8; mt++) {
            uint2 ov;
            ov.x = pk2bf(oacc[g][mt][0], oacc[g][mt][1]);
            ov.y = pk2bf(oacc[g][mt][2], oacc[g][mt][3]);
            *(uint2*)(Ob + mt * 16 + quad * 4) = ov;
        }
        if (quad == 0) lpart[sp * NQ + grow] = lrow[g];
    }
}

// ---------------------------------------------------------------------------
// Kernel 4: fused merge + trans-GEMM + BN stats. Unchanged.
// ---------------------------------------------------------------------------
__global__ __launch_bounds__(256) void tgemm_fused_kernel(
    const u16* __restrict__ Opart, const float* __restrict__ lpart,
    const u16* __restrict__ WT, float* __restrict__ C, float* __restrict__ stats)
{
    const int t    = threadIdx.x;
    const int w    = t >> 6;
    const int lane = t & 63;
    const int quad = lane >> 4;
    const int l15  = lane & 15;
    const int m0   = blockIdx.x * 64 + w * 16;
    const int row  = m0 + l15;

    float L = 0.f;
    #pragma unroll
    for (int s = 0; s < SPLIT; s++) L += lpart[s * NQ + row];
    float invL = 1.f / L;

    s16x8 af[4];
    #pragma unroll
    for (int ks = 0; ks < 4; ks++) {
        float sum[8] = {0.f, 0.f, 0.f, 0.f, 0.f, 0.f, 0.f, 0.f};
        #pragma unroll
        for (int s = 0; s < SPLIT; s++) {
            const u16* p = Opart + (size_t)s * NQ * NF + (size_t)row * NF + ks * 32 + quad * 8;
            ushort4 u0 = *(const ushort4*)p;
            ushort4 u1 = *(const ushort4*)(p + 4);
            sum[0] += b2f(u0.x); sum[1] += b2f(u0.y);
            sum[2] += b2f(u0.z); sum[3] += b2f(u0.w);
            sum[4] += b2f(u1.x); sum[5] += b2f(u1.y);
            sum[6] += b2f(u1.z); sum[7] += b2f(u1.w);
        }
        union { u16 a[8]; s16x8 v; } pk;
        #pragma unroll
        for (int j = 0; j < 8; j++) pk.a[j] = f2b(sum[j] * invL);
        af[ks] = pk.v;
    }

    f32x4 oacc[8];
    #pragma unroll
    for (int nt = 0; nt < 8; nt++) {
        oacc[nt] = (f32x4)0.f;
        const u16* Wp = WT + (size_t)(nt * 16 + l15) * NF + quad * 8;
        #pragma unroll
        for (int ks = 0; ks < 4; ks++) {
            s16x8 bf = *(const s16x8*)(Wp + ks * 32);
            oacc[nt] = __builtin_amdgcn_mfma_f32_16x16x32_bf16(af[ks], bf, oacc[nt], 0, 0, 0);
        }
    }

    float s[8], sq[8];
    #pragma unroll
    for (int nt = 0; nt < 8; nt++) {
        s[nt] = 0.f; sq[nt] = 0.f;
        #pragma unroll
        for (int r = 0; r < 4; r++) {
            float v = oacc[nt][r];
            C[(size_t)(m0 + quad * 4 + r) * NF + nt * 16 + l15] = v;
            s[nt] += v; sq[nt] += v * v;
        }
    }
    #pragma unroll
    for (int nt = 0; nt < 8; nt++) {
        s[nt]  += __shfl_xor(s[nt], 16);  s[nt]  += __shfl_xor(s[nt], 32);
        sq[nt] += __shfl_xor(sq[nt], 16); sq[nt] += __shfl_xor(sq[nt], 32);
    }
    __shared__ float red[2][4][128];
    if (quad == 0) {
        #pragma unroll
        for (int nt = 0; nt < 8; nt++) {
            red[0][w][nt * 16 + l15] = s[nt];
            red[1][w][nt * 16 + l15] = sq[nt];
        }
    }
    __syncthreads();
    if (t < 128) {
        float a = red[0][0][t] + red[0][1][t] + red[0][2][t] + red[0][3][t];
        atomicAdd(&stats[t], a);
    } else if (t < 256) {
        int f = t - 128;
        float a = red[1][0][f] + red[1][1][f] + red[1][2][f] + red[1][3][f];
        atomicAdd(&stats[128 + f], a);
    }
}

// ---------------------------------------------------------------------------
// Kernel 5: out = x_dec + BN(t). Unchanged.
// ---------------------------------------------------------------------------
__global__ __launch_bounds__(256) void bn_finalize(
    const float* __restrict__ tbuf, const float* __restrict__ xdec,
    const float* __restrict__ stats, const float* __restrict__ gamma,
    const float* __restrict__ beta, float* __restrict__ out)
{
    const int g = blockIdx.x * 256 + threadIdx.x;
    const int e = g * 4;
    const int f = e & (NF - 1);
    const float invN = 1.0f / (float)NQ;
    float4 tv = *(const float4*)(tbuf + e);
    float4 xv = *(const float4*)(xdec + e);
    float o[4], tt[4] = {tv.x, tv.y, tv.z, tv.w}, xx[4] = {xv.x, xv.y, xv.z, xv.w};
    #pragma unroll
    for (int u = 0; u < 4; u++) {
        float sum  = stats[f + u];
        float sumq = stats[128 + f + u];
        float mean = sum * invN;
        float var  = sumq * invN - mean * mean;
        float sc   = rsqrtf(var + BN_EPS) * gamma[f + u];
        o[u] = xx[u] + (tt[u] - mean) * sc + beta[f + u];
    }
    float4 ov = make_float4(o[0], o[1], o[2], o[3]);
    *(float4*)(out + e) = ov;
}

// ---------------------------------------------------------------------------
extern "C" void kernel_launch(void* const* d_in, const int* in_sizes, int n_in,
                              void* d_out, int out_size, void* d_ws, size_t ws_size,
                              hipStream_t stream) {
    const float* xdec_feat = (const float*)d_in[0];
    const float* xenc_feat = (const float*)d_in[1];
    const int*   nbr       = (const int*)d_in[2];
    const float* Wp1       = (const float*)d_in[3];
    const float* Wq        = (const float*)d_in[4];
    const float* Wk        = (const float*)d_in[5];
    const float* Wv        = (const float*)d_in[6];
    const float* Wt        = (const float*)d_in[7];
    const float* gamma     = (const float*)d_in[8];
    const float* beta      = (const float*)d_in[9];
    float* out = (float*)d_out;

    char* wsb = (char*)d_ws;
    const size_t MB = 1024 * 1024;
    float* xdec   = (float*)(wsb + 0);            //  0..8M   fp32 NQ*NF
    u16*   qbuf   = (u16*)  (wsb + 8 * MB);       //  8..12M  bf16 NQ*NF
    u16*   kbuf   = (u16*)  (wsb + 12 * MB);      // 12..20M  bf16 NKV*NF
    u16*   vt     = (u16*)  (wsb + 20 * MB);      // 20..28M  bf16 NKV*NF (V^T)
    u16*   opart  = (u16*)  (wsb + 28 * MB);      // 28..44M  bf16 SPLIT*NQ*NF
    u16*   xf_bf  = (u16*)  (wsb + 44 * MB);      // 2M
    u16*   wp1t   = (u16*)  (wsb + 46 * MB);      // ~432K
    u16*   wqT    = (u16*)  (wsb + 46 * MB + 512 * 1024);
    u16*   wkT    = (u16*)  (wsb + 46 * MB + 512 * 1024 + 32768);
    u16*   wvT    = (u16*)  (wsb + 46 * MB + 512 * 1024 + 49152);
    u16*   wtT    = (u16*)  (wsb + 46 * MB + 512 * 1024 + 65536);
    float* lpart  = (float*)(wsb + 47 * MB);
    float* stats  = (float*)(wsb + 47 * MB + 512 * 1024);
    float* tbuf   = (float*)(wsb + 12 * MB);      // reuses kbuf (dead after attn)

    prep_kernel<<<1289, 256, 0, stream>>>(
        xdec_feat, Wp1, Wq, Wk, Wv, Wt,
        xf_bf, wp1t, wqT, wkT, wvT, wtT, stats);
    main_fused_kernel<<<768, 256, 0, stream>>>(
        xenc_feat, xf_bf, nbr, wp1t, wqT, wkT, wvT,
        kbuf, vt, xdec, qbuf);
    attn_mfma_kernel<<<dim3(SQ / 128, BATCH, SPLIT), 256, 0, stream>>>(
        qbuf, kbuf, vt, opart, lpart);
    tgemm_fused_kernel<<<NQ / 64, 256, 0, stream>>>(opart, lpart, wtT, tbuf, stats);
    bn_finalize<<<(NQ * NF) / 1024, 256, 0, stream>>>(tbuf, xdec, stats, gamma, beta, out);
}

// Round 12
// 200.700 us; speedup vs baseline: 1.1303x; 1.1303x over previous
//
#include <hip/hip_runtime.h>
#include <math.h>

#define NQ      16384
#define NKV     32768
#define CIN     64
#define NF      128
#define NOFF    27
#define BATCH   8
#define SQ      2048
#define SKV     4096
#define BN_EPS  1e-4f
#define SPLIT   4
#define KV_PER_SPLIT (SKV / SPLIT)           // 1024
#define TILES_PER_SPLIT (KV_PER_SPLIT / 64)  // 16
#define LOG2E   1.4426950408889634f
#define SHIFT2  57.70780163555854f           // 40 * log2(e)

typedef unsigned short u16;
typedef unsigned int   u32;
typedef __attribute__((ext_vector_type(4))) float f32x4;
typedef __attribute__((ext_vector_type(8))) short s16x8;

__device__ __forceinline__ u16 f2b(float x) {
    union { float f; unsigned u; } c; c.f = x;
    unsigned r = (c.u + 0x7FFFu + ((c.u >> 16) & 1u)) >> 16;
    return (u16)r;
}
__device__ __forceinline__ float b2f(u16 x) {
    union { unsigned u; float f; } c; c.u = ((unsigned)x) << 16;
    return c.f;
}
__device__ __forceinline__ u32 pk2bf(float lo, float hi) {
    union { float f; u32 u; } a, b;
    a.f = lo; b.f = hi;
    return __builtin_amdgcn_perm(b.u + 0x8000u, a.u + 0x8000u, 0x07060302u);
}
__device__ __forceinline__ void g2l16(const void* gp, void* lp) {
    __builtin_amdgcn_global_load_lds(
        (const __attribute__((address_space(1))) unsigned*)gp,
        (__attribute__((address_space(3))) unsigned*)lp, 16, 0, 0);
}

// ---------------------------------------------------------------------------
// Kernel 1 (prep): unchanged.
// ---------------------------------------------------------------------------
__device__ __forceinline__ void wtrans_one(
    const float* __restrict__ src, u16* __restrict__ dst, int K, int id, float sc)
{
    int n  = id / (K / 4);
    int k4 = (id % (K / 4)) * 4;
    const float* s = src + (size_t)k4 * NF + n;
    ushort4 o;
    o.x = f2b(s[0] * sc); o.y = f2b(s[NF] * sc);
    o.z = f2b(s[2 * NF] * sc); o.w = f2b(s[3 * NF] * sc);
    *(ushort4*)(dst + (size_t)n * K + k4) = o;
}

__global__ __launch_bounds__(256) void prep_kernel(
    const float* __restrict__ xdec_feat, const float* __restrict__ Wp1,
    const float* __restrict__ Wq, const float* __restrict__ Wk,
    const float* __restrict__ Wv, const float* __restrict__ Wt,
    u16* __restrict__ xf_bf, u16* __restrict__ wp1t,
    u16* __restrict__ wqT, u16* __restrict__ wkT,
    u16* __restrict__ wvT, u16* __restrict__ wtT,
    float* __restrict__ stats)
{
    int bid = blockIdx.x;
    int t   = threadIdx.x;
    if (bid < 1024) {
        int i = (bid * 256 + t) * 4;
        float4 v = *(const float4*)(xdec_feat + i);
        ushort4 o;
        o.x = f2b(v.x); o.y = f2b(v.y); o.z = f2b(v.z); o.w = f2b(v.w);
        *(ushort4*)(xf_bf + i) = o;
    } else if (bid < 1240) {
        int id = (bid - 1024) * 256 + t;
        int ko = id >> 11;
        int r  = id & 2047;
        int f  = r >> 4;
        int c4 = (r & 15) * 4;
        const float* s = Wp1 + (size_t)ko * 8192 + (size_t)c4 * NF + f;
        ushort4 o;
        o.x = f2b(s[0]); o.y = f2b(s[NF]); o.z = f2b(s[2 * NF]); o.w = f2b(s[3 * NF]);
        *(ushort4*)(wp1t + (size_t)ko * 8192 + (size_t)f * 64 + c4) = o;
    } else if (bid < 1288) {
        int id = (bid - 1240) * 256 + t;
        if (id < 4096)        wtrans_one(Wq, wqT, 128, id, LOG2E);
        else if (id < 6144)   wtrans_one(Wk, wkT, 64, id - 4096, 1.f);
        else if (id < 8192)   wtrans_one(Wv, wvT, 64, id - 6144, 1.f);
        else                  wtrans_one(Wt, wtT, 128, id - 8192, 1.f);
    } else {
        stats[t] = 0.f;
    }
}

// ---------------------------------------------------------------------------
// Kernel 2 (main_fused):
//  blocks [0,512): KV GEMM; V^T via LDS tile + coalesced uint4 writeout.
//  blocks [512,768): p1conv MFMA (dbuf B staging + A-fragment prefetch)
//                    + fused q-GEMM.
// ---------------------------------------------------------------------------
__global__ __launch_bounds__(256) void main_fused_kernel(
    const float* __restrict__ xenc, const u16* __restrict__ xf,
    const int* __restrict__ nbr, const u16* __restrict__ wp1t,
    const u16* __restrict__ wqT, const u16* __restrict__ wkT,
    const u16* __restrict__ wvT,
    u16* __restrict__ kbuf, u16* __restrict__ vt,
    float* __restrict__ xdec, u16* __restrict__ qbuf)
{
    __shared__ u16 smem[2][128][64];   // p1conv B dbuf / KV-half V^T tile
    __shared__ int nbr_s[64][28];

    const int t    = threadIdx.x;
    const int w    = t >> 6;
    const int lane = t & 63;
    const int quad = lane >> 4;
    const int l15  = lane & 15;

    if (blockIdx.x < 512) {
        // ---------------- KV GEMM ----------------
        const int bm0 = blockIdx.x * 64;
        const int m0  = bm0 + w * 16;
        const float* Ap = xenc + (size_t)(m0 + l15) * CIN + quad * 8;
        float4 a0 = *(const float4*)(Ap);
        float4 a1 = *(const float4*)(Ap + 4);
        float4 a2 = *(const float4*)(Ap + 32);
        float4 a3 = *(const float4*)(Ap + 36);
        union { u16 a[8]; s16x8 v; } p0, p1;
        p0.a[0] = f2b(a0.x); p0.a[1] = f2b(a0.y); p0.a[2] = f2b(a0.z); p0.a[3] = f2b(a0.w);
        p0.a[4] = f2b(a1.x); p0.a[5] = f2b(a1.y); p0.a[6] = f2b(a1.z); p0.a[7] = f2b(a1.w);
        p1.a[0] = f2b(a2.x); p1.a[1] = f2b(a2.y); p1.a[2] = f2b(a2.z); p1.a[3] = f2b(a2.w);
        p1.a[4] = f2b(a3.x); p1.a[5] = f2b(a3.y); p1.a[6] = f2b(a3.z); p1.a[7] = f2b(a3.w);
        s16x8 af0 = p0.v, af1 = p1.v;

        u16* vtile = &smem[0][0][0];   // [128][64] view, 16 KB
        #pragma unroll
        for (int nt = 0; nt < 8; nt++) {
            f32x4 ka = (f32x4)0.f, va = (f32x4)0.f;
            const u16* Kp = wkT + (size_t)(nt * 16 + l15) * CIN + quad * 8;
            const u16* Vp = wvT + (size_t)(nt * 16 + l15) * CIN + quad * 8;
            s16x8 kb0 = *(const s16x8*)(Kp);
            s16x8 kb1 = *(const s16x8*)(Kp + 32);
            s16x8 vb0 = *(const s16x8*)(Vp);
            s16x8 vb1 = *(const s16x8*)(Vp + 32);
            ka = __builtin_amdgcn_mfma_f32_16x16x32_bf16(af0, kb0, ka, 0, 0, 0);
            ka = __builtin_amdgcn_mfma_f32_16x16x32_bf16(af1, kb1, ka, 0, 0, 0);
            va = __builtin_amdgcn_mfma_f32_16x16x32_bf16(af0, vb0, va, 0, 0, 0);
            va = __builtin_amdgcn_mfma_f32_16x16x32_bf16(af1, vb1, va, 0, 0, 0);
            #pragma unroll
            for (int r = 0; r < 4; r++)
                kbuf[(size_t)(m0 + quad * 4 + r) * NF + nt * 16 + l15] = f2b(ka[r]);
            ushort4 pk;
            pk.x = f2b(va[0]); pk.y = f2b(va[1]); pk.z = f2b(va[2]); pk.w = f2b(va[3]);
            *(ushort4*)&vtile[(nt * 16 + l15) * 64 + w * 16 + quad * 4] = pk;
        }
        __syncthreads();
        // coalesced writeout: 128 f-rows x 8 chunks x 16B (uint4 = 8 u16)
        int bb  = bm0 >> 12;
        int kv0 = bm0 & 4095;
        #pragma unroll
        for (int it = 0; it < 4; it++) {
            int idx = it * 256 + t;
            int row = idx >> 3;
            int ch  = idx & 7;
            *(uint4*)(vt + (size_t)(bb * NF + row) * SKV + kv0 + ch * 8) =
                *(const uint4*)&vtile[row * 64 + ch * 8];
        }
        return;
    }

    // ---------------- p1conv + q ----------------
    const int base = (blockIdx.x - 512) * 64;

    for (int i = t; i < 64 * NOFF; i += 256)
        nbr_s[i / NOFF][i % NOFF] = nbr[(size_t)base * NOFF + i];

    f32x4 oacc[8];
    #pragma unroll
    for (int n = 0; n < 8; n++) oacc[n] = (f32x4)0.f;

    const int arow = w * 16 + l15;
    const int sr   = w * 32 + (lane >> 3);

    #pragma unroll
    for (int c = 0; c < 4; c++) {
        int row = sr + c * 8;
        int kk  = (lane & 7) ^ (row & 7);
        g2l16(wp1t + (size_t)row * 64 + kk * 8, &smem[0][w * 32 + c * 8][0]);
    }
    __syncthreads();   // nbr_s ready AND Bs[0] drained

    // A-fragments for ko=0 (after barrier: nbr_s valid)
    int nb0 = nbr_s[arow][0];
    s16x8 af0 = *(const s16x8*)(xf + (size_t)nb0 * CIN + quad * 8);
    s16x8 af1 = *(const s16x8*)(xf + (size_t)nb0 * CIN + quad * 8 + 32);

    for (int ko = 0; ko < NOFF; ko++) {
        int cur = ko & 1;
        s16x8 nf0, nf1;
        if (ko + 1 < NOFF) {
            int nxt = (ko + 1) & 1;
            #pragma unroll
            for (int c = 0; c < 4; c++) {
                int row = sr + c * 8;
                int kk  = (lane & 7) ^ (row & 7);
                g2l16(wp1t + (size_t)(ko + 1) * 8192 + (size_t)row * 64 + kk * 8,
                      &smem[nxt][w * 32 + c * 8][0]);
            }
            // prefetch next A-fragments (latency hidden behind this ko's MFMAs)
            int nb = nbr_s[arow][ko + 1];
            nf0 = *(const s16x8*)(xf + (size_t)nb * CIN + quad * 8);
            nf1 = *(const s16x8*)(xf + (size_t)nb * CIN + quad * 8 + 32);
        }
        #pragma unroll
        for (int nt = 0; nt < 8; nt++) {
            int pc0 = quad ^ (l15 & 7);
            int pc1 = (4 + quad) ^ (l15 & 7);
            s16x8 bf0 = *(const s16x8*)&smem[cur][nt * 16 + l15][pc0 * 8];
            s16x8 bf1 = *(const s16x8*)&smem[cur][nt * 16 + l15][pc1 * 8];
            oacc[nt] = __builtin_amdgcn_mfma_f32_16x16x32_bf16(af0, bf0, oacc[nt], 0, 0, 0);
            oacc[nt] = __builtin_amdgcn_mfma_f32_16x16x32_bf16(af1, bf1, oacc[nt], 0, 0, 0);
        }
        af0 = nf0;
        af1 = nf1;
        __syncthreads();
    }

    u16* xq = &smem[0][0][0];   // [64][136] view
    #pragma unroll
    for (int nt = 0; nt < 8; nt++)
        #pragma unroll
        for (int r = 0; r < 4; r++) {
            int row = w * 16 + quad * 4 + r;
            int col = nt * 16 + l15;
            xdec[(size_t)(base + row) * NF + col] = oacc[nt][r];
            xq[row * 136 + col] = f2b(oacc[nt][r]);
        }

    s16x8 aq[4];
    #pragma unroll
    for (int ks = 0; ks < 4; ks++)
        aq[ks] = *(const s16x8*)&xq[(w * 16 + l15) * 136 + ks * 32 + quad * 8];

    #pragma unroll
    for (int nt = 0; nt < 8; nt++) {
        f32x4 acc = (f32x4)0.f;
        const u16* Wp = wqT + (size_t)(nt * 16 + l15) * NF + quad * 8;
        #pragma unroll
        for (int ks = 0; ks < 4; ks++) {
            s16x8 bf = *(const s16x8*)(Wp + ks * 32);
            acc = __builtin_amdgcn_mfma_f32_16x16x32_bf16(aq[ks], bf, acc, 0, 0, 0);
        }
        #pragma unroll
        for (int r = 0; r < 4; r++)
            qbuf[(size_t)(base + w * 16 + quad * 4 + r) * NF + nt * 16 + l15] = f2b(acc[r]);
    }
}

// ---------------------------------------------------------------------------
// Kernel 3: MFMA flash attention — EXACT R9 kernel (known 63us, correct).
// 128 q/block, double-buffered K+V LDS staging, 1 barrier/tile.
// ---------------------------------------------------------------------------
__global__ __launch_bounds__(256) void attn_mfma_kernel(
    const u16* __restrict__ Q, const u16* __restrict__ K,
    const u16* __restrict__ Vt, u16* __restrict__ Opart,
    float* __restrict__ lpart)
{
    __shared__ u16 Ks[2][64][128];  // [buf][kv][f] phys chunk = k8 ^ (row&15)
    __shared__ u16 Vs[2][128][64];  // [buf][f][kv] phys chunk = k8 ^ (row&7)
    __shared__ u16 Ps[4][16][72];

    const int t    = threadIdx.x;
    const int b    = blockIdx.y;
    const int q0   = blockIdx.x * 128;
    const int sp   = blockIdx.z;
    const int w    = t >> 6;
    const int lane = t & 63;
    const int quad = lane >> 4;
    const int l15  = lane & 15;

    const u16* Kb  = K  + (size_t)b * SKV * NF;
    const u16* Vtb = Vt + (size_t)b * NF * SKV;

    s16x8 qf[2][4];
    #pragma unroll
    for (int g = 0; g < 2; g++) {
        const u16* Qp = Q + ((size_t)(b * SQ + q0 + w * 32 + g * 16 + l15)) * NF + quad * 8;
        #pragma unroll
        for (int ks = 0; ks < 4; ks++) qf[g][ks] = *(const s16x8*)(Qp + ks * 32);
    }

    f32x4 oacc[2][8];
    #pragma unroll
    for (int g = 0; g < 2; g++)
        #pragma unroll
        for (int n = 0; n < 8; n++) oacc[g][n] = (f32x4)0.f;
    float lrow[2] = {0.f, 0.f};

    const int kvbase = sp * KV_PER_SPLIT;
    const int krow = w * 16 + (lane >> 4);
    const int vrow = w * 32 + (lane >> 3);

    #pragma unroll
    for (int c = 0; c < 4; c++) {
        int row = krow + c * 4;
        int k8  = (lane & 15) ^ (row & 15);
        g2l16(Kb + (size_t)(kvbase + row) * NF + k8 * 8, &Ks[0][w * 16 + c * 4][0]);
    }
    #pragma unroll
    for (int c = 0; c < 4; c++) {
        int row = vrow + c * 8;
        int k8  = (lane & 7) ^ (row & 7);
        g2l16(Vtb + (size_t)row * SKV + kvbase + k8 * 8, &Vs[0][w * 32 + c * 8][0]);
    }

    for (int tile = 0; tile < TILES_PER_SPLIT; tile++) {
        const int cur = tile & 1;
        __syncthreads();
        if (tile + 1 < TILES_PER_SPLIT) {
            const int nxt = (tile + 1) & 1;
            int kvn = kvbase + (tile + 1) * 64;
            #pragma unroll
            for (int c = 0; c < 4; c++) {
                int row = krow + c * 4;
                int k8  = (lane & 15) ^ (row & 15);
                g2l16(Kb + (size_t)(kvn + row) * NF + k8 * 8, &Ks[nxt][w * 16 + c * 4][0]);
            }
            #pragma unroll
            for (int c = 0; c < 4; c++) {
                int row = vrow + c * 8;
                int k8  = (lane & 7) ^ (row & 7);
                g2l16(Vtb + (size_t)row * SKV + kvn + k8 * 8, &Vs[nxt][w * 32 + c * 8][0]);
            }
        }

        f32x4 sacc[2][4];
        #pragma unroll
        for (int c = 0; c < 4; c++) {
            sacc[0][c] = (f32x4)0.f;
            sacc[1][c] = (f32x4)0.f;
            #pragma unroll
            for (int ks = 0; ks < 4; ks++) {
                int p = (ks * 4 + quad) ^ l15;
                s16x8 ka = *(const s16x8*)&Ks[cur][c * 16 + l15][p * 8];
                sacc[0][c] = __builtin_amdgcn_mfma_f32_16x16x32_bf16(ka, qf[0][ks], sacc[0][c], 0, 0, 0);
                sacc[1][c] = __builtin_amdgcn_mfma_f32_16x16x32_bf16(ka, qf[1][ks], sacc[1][c], 0, 0, 0);
            }
        }

        s16x8 pb[2][2];
        #pragma unroll
        for (int g = 0; g < 2; g++) {
            float rs = 0.f;
            float pv[4][4];
            #pragma unroll
            for (int c = 0; c < 4; c++)
                #pragma unroll
                for (int r = 0; r < 4; r++) {
                    float p = exp2f(sacc[g][c][r] - SHIFT2);
                    pv[c][r] = p;
                    rs += p;
                }
            rs += __shfl_xor(rs, 16);
            rs += __shfl_xor(rs, 32);
            lrow[g] += rs;
            #pragma unroll
            for (int c = 0; c < 4; c++) {
                uint2 pk;
                pk.x = pk2bf(pv[c][0], pv[c][1]);
                pk.y = pk2bf(pv[c][2], pv[c][3]);
                *(uint2*)&Ps[w][l15][c * 16 + quad * 4] = pk;
            }
            pb[g][0] = *(const s16x8*)&Ps[w][l15][quad * 8];
            pb[g][1] = *(const s16x8*)&Ps[w][l15][32 + quad * 8];
        }

        #pragma unroll
        for (int mt = 0; mt < 8; mt++) {
            int p0 = quad ^ (l15 & 7);
            int p1 = (4 + quad) ^ (l15 & 7);
            s16x8 va0 = *(const s16x8*)&Vs[cur][mt * 16 + l15][p0 * 8];
            s16x8 va1 = *(const s16x8*)&Vs[cur][mt * 16 + l15][p1 * 8];
            oacc[0][mt] = __builtin_amdgcn_mfma_f32_16x16x32_bf16(va0, pb[0][0], oacc[0][mt], 0, 0, 0);
            oacc[0][mt] = __builtin_amdgcn_mfma_f32_16x16x32_bf16(va1, pb[0][1], oacc[0][mt], 0, 0, 0);
            oacc[1][mt] = __builtin_amdgcn_mfma_f32_16x16x32_bf16(va0, pb[1][0], oacc[1][mt], 0, 0, 0);
            oacc[1][mt] = __builtin_amdgcn_mfma_f32_16x16x32_bf16(va1, pb[1][1], oacc[1][mt], 0, 0, 0);
        }
    }

    #pragma unroll
    for (int g = 0; g < 2; g++) {
        int grow = b * SQ + q0 + w * 32 + g * 16 + l15;
        u16* Ob = Opart + (size_t)sp * NQ * NF + (size_t)grow * NF;
        #pragma unroll
        for (int mt = 0; mt < 8; mt++) {
            uint2 ov;
            ov.x = pk2bf(oacc[g][mt][0], oacc[g][mt][1]);
            ov.y = pk2bf(oacc[g][mt][2], oacc[g][mt][3]);
            *(uint2*)(Ob + mt * 16 + quad * 4) = ov;
        }
        if (quad == 0) lpart[sp * NQ + grow] = lrow[g];
    }
}

// ---------------------------------------------------------------------------
// Kernel 4: fused merge + trans-GEMM + BN stats, N-SPLIT x2 for TLP.
// grid = (NQ/64, 2); blockIdx.y picks feature half (4 nt of 8).
// ---------------------------------------------------------------------------
__global__ __launch_bounds__(256) void tgemm_fused_kernel(
    const u16* __restrict__ Opart, const float* __restrict__ lpart,
    const u16* __restrict__ WT, float* __restrict__ C, float* __restrict__ stats)
{
    const int t    = threadIdx.x;
    const int w    = t >> 6;
    const int lane = t & 63;
    const int quad = lane >> 4;
    const int l15  = lane & 15;
    const int m0   = blockIdx.x * 64 + w * 16;
    const int row  = m0 + l15;
    const int ny   = blockIdx.y;          // feature half: nt in [ny*4, ny*4+4)

    float L = 0.f;
    #pragma unroll
    for (int s = 0; s < SPLIT; s++) L += lpart[s * NQ + row];
    float invL = 1.f / L;

    s16x8 af[4];
    #pragma unroll
    for (int ks = 0; ks < 4; ks++) {
        float sum[8] = {0.f, 0.f, 0.f, 0.f, 0.f, 0.f, 0.f, 0.f};
        #pragma unroll
        for (int s = 0; s < SPLIT; s++) {
            const u16* p = Opart + (size_t)s * NQ * NF + (size_t)row * NF + ks * 32 + quad * 8;
            ushort4 u0 = *(const ushort4*)p;
            ushort4 u1 = *(const ushort4*)(p + 4);
            sum[0] += b2f(u0.x); sum[1] += b2f(u0.y);
            sum[2] += b2f(u0.z); sum[3] += b2f(u0.w);
            sum[4] += b2f(u1.x); sum[5] += b2f(u1.y);
            sum[6] += b2f(u1.z); sum[7] += b2f(u1.w);
        }
        union { u16 a[8]; s16x8 v; } pk;
        #pragma unroll
        for (int j = 0; j < 8; j++) pk.a[j] = f2b(sum[j] * invL);
        af[ks] = pk.v;
    }

    f32x4 oacc[4];
    #pragma unroll
    for (int nt = 0; nt < 4; nt++) {
        oacc[nt] = (f32x4)0.f;
        const u16* Wp = WT + (size_t)(ny * 64 + nt * 16 + l15) * NF + quad * 8;
        #pragma unroll
        for (int ks = 0; ks < 4; ks++) {
            s16x8 bf = *(const s16x8*)(Wp + ks * 32);
            oacc[nt] = __builtin_amdgcn_mfma_f32_16x16x32_bf16(af[ks], bf, oacc[nt], 0, 0, 0);
        }
    }

    float s[4], sq[4];
    #pragma unroll
    for (int nt = 0; nt < 4; nt++) {
        s[nt] = 0.f; sq[nt] = 0.f;
        #pragma unroll
        for (int r = 0; r < 4; r++) {
            float v = oacc[nt][r];
            C[(size_t)(m0 + quad * 4 + r) * NF + ny * 64 + nt * 16 + l15] = v;
            s[nt] += v; sq[nt] += v * v;
        }
    }
    #pragma unroll
    for (int nt = 0; nt < 4; nt++) {
        s[nt]  += __shfl_xor(s[nt], 16);  s[nt]  += __shfl_xor(s[nt], 32);
        sq[nt] += __shfl_xor(sq[nt], 16); sq[nt] += __shfl_xor(sq[nt], 32);
    }
    __shared__ float red[2][4][64];
    if (quad == 0) {
        #pragma unroll
        for (int nt = 0; nt < 4; nt++) {
            red[0][w][nt * 16 + l15] = s[nt];
            red[1][w][nt * 16 + l15] = sq[nt];
        }
    }
    __syncthreads();
    if (t < 64) {
        float a = red[0][0][t] + red[0][1][t] + red[0][2][t] + red[0][3][t];
        atomicAdd(&stats[ny * 64 + t], a);
    } else if (t < 128) {
        int f = t - 64;
        float a = red[1][0][f] + red[1][1][f] + red[1][2][f] + red[1][3][f];
        atomicAdd(&stats[128 + ny * 64 + f], a);
    }
}

// ---------------------------------------------------------------------------
// Kernel 5: out = x_dec + BN(t). Unchanged.
// ---------------------------------------------------------------------------
__global__ __launch_bounds__(256) void bn_finalize(
    const float* __restrict__ tbuf, const float* __restrict__ xdec,
    const float* __restrict__ stats, const float* __restrict__ gamma,
    const float* __restrict__ beta, float* __restrict__ out)
{
    const int g = blockIdx.x * 256 + threadIdx.x;
    const int e = g * 4;
    const int f = e & (NF - 1);
    const float invN = 1.0f / (float)NQ;
    float4 tv = *(const float4*)(tbuf + e);
    float4 xv = *(const float4*)(xdec + e);
    float o[4], tt[4] = {tv.x, tv.y, tv.z, tv.w}, xx[4] = {xv.x, xv.y, xv.z, xv.w};
    #pragma unroll
    for (int u = 0; u < 4; u++) {
        float sum  = stats[f + u];
        float sumq = stats[128 + f + u];
        float mean = sum * invN;
        float var  = sumq * invN - mean * mean;
        float sc   = rsqrtf(var + BN_EPS) * gamma[f + u];
        o[u] = xx[u] + (tt[u] - mean) * sc + beta[f + u];
    }
    float4 ov = make_float4(o[0], o[1], o[2], o[3]);
    *(float4*)(out + e) = ov;
}

// ---------------------------------------------------------------------------
extern "C" void kernel_launch(void* const* d_in, const int* in_sizes, int n_in,
                              void* d_out, int out_size, void* d_ws, size_t ws_size,
                              hipStream_t stream) {
    const float* xdec_feat = (const float*)d_in[0];
    const float* xenc_feat = (const float*)d_in[1];
    const int*   nbr       = (const int*)d_in[2];
    const float* Wp1       = (const float*)d_in[3];
    const float* Wq        = (const float*)d_in[4];
    const float* Wk        = (const float*)d_in[5];
    const float* Wv        = (const float*)d_in[6];
    const float* Wt        = (const float*)d_in[7];
    const float* gamma     = (const float*)d_in[8];
    const float* beta      = (const float*)d_in[9];
    float* out = (float*)d_out;

    char* wsb = (char*)d_ws;
    const size_t MB = 1024 * 1024;
    float* xdec   = (float*)(wsb + 0);            //  0..8M   fp32 NQ*NF
    u16*   qbuf   = (u16*)  (wsb + 8 * MB);       //  8..12M  bf16 NQ*NF
    u16*   kbuf   = (u16*)  (wsb + 12 * MB);      // 12..20M  bf16 NKV*NF
    u16*   vt     = (u16*)  (wsb + 20 * MB);      // 20..28M  bf16 NKV*NF (V^T)
    u16*   opart  = (u16*)  (wsb + 28 * MB);      // 28..44M  bf16 SPLIT*NQ*NF
    u16*   xf_bf  = (u16*)  (wsb + 44 * MB);      // 2M
    u16*   wp1t   = (u16*)  (wsb + 46 * MB);      // ~432K
    u16*   wqT    = (u16*)  (wsb + 46 * MB + 512 * 1024);
    u16*   wkT    = (u16*)  (wsb + 46 * MB + 512 * 1024 + 32768);
    u16*   wvT    = (u16*)  (wsb + 46 * MB + 512 * 1024 + 49152);
    u16*   wtT    = (u16*)  (wsb + 46 * MB + 512 * 1024 + 65536);
    float* lpart  = (float*)(wsb + 47 * MB);
    float* stats  = (float*)(wsb + 47 * MB + 512 * 1024);
    float* tbuf   = (float*)(wsb + 12 * MB);      // reuses kbuf (dead after attn)

    prep_kernel<<<1289, 256, 0, stream>>>(
        xdec_feat, Wp1, Wq, Wk, Wv, Wt,
        xf_bf, wp1t, wqT, wkT, wvT, wtT, stats);
    main_fused_kernel<<<768, 256, 0, stream>>>(
        xenc_feat, xf_bf, nbr, wp1t, wqT, wkT, wvT,
        kbuf, vt, xdec, qbuf);
    attn_mfma_kernel<<<dim3(SQ / 128, BATCH, SPLIT), 256, 0, stream>>>(
        qbuf, kbuf, vt, opart, lpart);
    tgemm_fused_kernel<<<dim3(NQ / 64, 2), 256, 0, stream>>>(opart, lpart, wtT, tbuf, stats);
    bn_finalize<<<(NQ * NF) / 1024, 256, 0, stream>>>(tbuf, xdec, stats, gamma, beta, out);
}

// Round 13
// 190.481 us; speedup vs baseline: 1.1910x; 1.0537x over previous
//
#include <hip/hip_runtime.h>
#include <math.h>

#define NQ      16384
#define NKV     32768
#define CIN     64
#define NF      128
#define NOFF    27
#define BATCH   8
#define SQ      2048
#define SKV     4096
#define BN_EPS  1e-4f
#define SPLIT   4
#define KV_PER_SPLIT (SKV / SPLIT)           // 1024
#define TILES_PER_SPLIT (KV_PER_SPLIT / 64)  // 16
#define SOFTMAX_SHIFT 40.0f                  // static max (validated R5-R7)

typedef unsigned short u16;
typedef unsigned int   u32;
typedef __attribute__((ext_vector_type(4))) float f32x4;
typedef __attribute__((ext_vector_type(8))) short s16x8;

__device__ __forceinline__ u16 f2b(float x) {
    union { float f; unsigned u; } c; c.f = x;
    unsigned r = (c.u + 0x7FFFu + ((c.u >> 16) & 1u)) >> 16;
    return (u16)r;
}
__device__ __forceinline__ float b2f(u16 x) {
    union { unsigned u; float f; } c; c.u = ((unsigned)x) << 16;
    return c.f;
}
__device__ __forceinline__ u32 pk2bf(float lo, float hi) {
    union { float f; u32 u; } a, b;
    a.f = lo; b.f = hi;
    return __builtin_amdgcn_perm(b.u + 0x8000u, a.u + 0x8000u, 0x07060302u);
}
__device__ __forceinline__ void g2l16(const void* gp, void* lp) {
    __builtin_amdgcn_global_load_lds(
        (const __attribute__((address_space(1))) unsigned*)gp,
        (__attribute__((address_space(3))) unsigned*)lp, 16, 0, 0);
}

// ---------------------------------------------------------------------------
// Kernel 1 (prep): xdec_feat->bf16, Wp1->wp1t, 4 weights->WT (no prescale),
// stats zero. grid = 1289.
// ---------------------------------------------------------------------------
__device__ __forceinline__ void wtrans_one(
    const float* __restrict__ src, u16* __restrict__ dst, int K, int id)
{
    int n  = id / (K / 4);
    int k4 = (id % (K / 4)) * 4;
    const float* s = src + (size_t)k4 * NF + n;
    ushort4 o;
    o.x = f2b(s[0]); o.y = f2b(s[NF]);
    o.z = f2b(s[2 * NF]); o.w = f2b(s[3 * NF]);
    *(ushort4*)(dst + (size_t)n * K + k4) = o;
}

__global__ __launch_bounds__(256) void prep_kernel(
    const float* __restrict__ xdec_feat, const float* __restrict__ Wp1,
    const float* __restrict__ Wq, const float* __restrict__ Wk,
    const float* __restrict__ Wv, const float* __restrict__ Wt,
    u16* __restrict__ xf_bf, u16* __restrict__ wp1t,
    u16* __restrict__ wqT, u16* __restrict__ wkT,
    u16* __restrict__ wvT, u16* __restrict__ wtT,
    float* __restrict__ stats)
{
    int bid = blockIdx.x;
    int t   = threadIdx.x;
    if (bid < 1024) {
        int i = (bid * 256 + t) * 4;
        float4 v = *(const float4*)(xdec_feat + i);
        ushort4 o;
        o.x = f2b(v.x); o.y = f2b(v.y); o.z = f2b(v.z); o.w = f2b(v.w);
        *(ushort4*)(xf_bf + i) = o;
    } else if (bid < 1240) {
        int id = (bid - 1024) * 256 + t;
        int ko = id >> 11;
        int r  = id & 2047;
        int f  = r >> 4;
        int c4 = (r & 15) * 4;
        const float* s = Wp1 + (size_t)ko * 8192 + (size_t)c4 * NF + f;
        ushort4 o;
        o.x = f2b(s[0]); o.y = f2b(s[NF]); o.z = f2b(s[2 * NF]); o.w = f2b(s[3 * NF]);
        *(ushort4*)(wp1t + (size_t)ko * 8192 + (size_t)f * 64 + c4) = o;
    } else if (bid < 1288) {
        int id = (bid - 1240) * 256 + t;
        if (id < 4096)        wtrans_one(Wq, wqT, 128, id);
        else if (id < 6144)   wtrans_one(Wk, wkT, 64, id - 4096);
        else if (id < 8192)   wtrans_one(Wv, wvT, 64, id - 6144);
        else                  wtrans_one(Wt, wtT, 128, id - 8192);
    } else {
        stats[t] = 0.f;
    }
}

// ---------------------------------------------------------------------------
// Kernel 2 (main_fused): EXACT R9 version.
//  blocks [0,512): KV GEMM, inline fp32->bf16 A-conversion, scattered vt writes.
//  blocks [512,768): p1conv MFMA (dbuf B staging) + fused q-GEMM.
// ---------------------------------------------------------------------------
__global__ __launch_bounds__(256) void main_fused_kernel(
    const float* __restrict__ xenc, const u16* __restrict__ xf,
    const int* __restrict__ nbr, const u16* __restrict__ wp1t,
    const u16* __restrict__ wqT, const u16* __restrict__ wkT,
    const u16* __restrict__ wvT,
    u16* __restrict__ kbuf, u16* __restrict__ vt,
    float* __restrict__ xdec, u16* __restrict__ qbuf)
{
    __shared__ u16 Bs[2][128][64];
    __shared__ int nbr_s[64][28];

    const int t    = threadIdx.x;
    const int w    = t >> 6;
    const int lane = t & 63;
    const int quad = lane >> 4;
    const int l15  = lane & 15;

    if (blockIdx.x < 512) {
        const int m0 = blockIdx.x * 64 + w * 16;
        const float* Ap = xenc + (size_t)(m0 + l15) * CIN + quad * 8;
        float4 a0 = *(const float4*)(Ap);
        float4 a1 = *(const float4*)(Ap + 4);
        float4 a2 = *(const float4*)(Ap + 32);
        float4 a3 = *(const float4*)(Ap + 36);
        union { u16 a[8]; s16x8 v; } p0, p1;
        p0.a[0] = f2b(a0.x); p0.a[1] = f2b(a0.y); p0.a[2] = f2b(a0.z); p0.a[3] = f2b(a0.w);
        p0.a[4] = f2b(a1.x); p0.a[5] = f2b(a1.y); p0.a[6] = f2b(a1.z); p0.a[7] = f2b(a1.w);
        p1.a[0] = f2b(a2.x); p1.a[1] = f2b(a2.y); p1.a[2] = f2b(a2.z); p1.a[3] = f2b(a2.w);
        p1.a[4] = f2b(a3.x); p1.a[5] = f2b(a3.y); p1.a[6] = f2b(a3.z); p1.a[7] = f2b(a3.w);
        s16x8 af0 = p0.v, af1 = p1.v;

        int m  = m0 + quad * 4;
        int bb = m >> 12;
        int kv = m & 4095;
        #pragma unroll
        for (int nt = 0; nt < 8; nt++) {
            f32x4 ka = (f32x4)0.f, va = (f32x4)0.f;
            const u16* Kp = wkT + (size_t)(nt * 16 + l15) * CIN + quad * 8;
            const u16* Vp = wvT + (size_t)(nt * 16 + l15) * CIN + quad * 8;
            s16x8 kb0 = *(const s16x8*)(Kp);
            s16x8 kb1 = *(const s16x8*)(Kp + 32);
            s16x8 vb0 = *(const s16x8*)(Vp);
            s16x8 vb1 = *(const s16x8*)(Vp + 32);
            ka = __builtin_amdgcn_mfma_f32_16x16x32_bf16(af0, kb0, ka, 0, 0, 0);
            ka = __builtin_amdgcn_mfma_f32_16x16x32_bf16(af1, kb1, ka, 0, 0, 0);
            va = __builtin_amdgcn_mfma_f32_16x16x32_bf16(af0, vb0, va, 0, 0, 0);
            va = __builtin_amdgcn_mfma_f32_16x16x32_bf16(af1, vb1, va, 0, 0, 0);
            #pragma unroll
            for (int r = 0; r < 4; r++)
                kbuf[(size_t)(m0 + quad * 4 + r) * NF + nt * 16 + l15] = f2b(ka[r]);
            ushort4 pk;
            pk.x = f2b(va[0]); pk.y = f2b(va[1]); pk.z = f2b(va[2]); pk.w = f2b(va[3]);
            *(ushort4*)(vt + (size_t)(bb * NF + nt * 16 + l15) * SKV + kv) = pk;
        }
        return;
    }

    const int base = (blockIdx.x - 512) * 64;

    for (int i = t; i < 64 * NOFF; i += 256)
        nbr_s[i / NOFF][i % NOFF] = nbr[(size_t)base * NOFF + i];

    f32x4 oacc[8];
    #pragma unroll
    for (int n = 0; n < 8; n++) oacc[n] = (f32x4)0.f;

    const int arow = w * 16 + l15;
    const int sr   = w * 32 + (lane >> 3);

    #pragma unroll
    for (int c = 0; c < 4; c++) {
        int row = sr + c * 8;
        int kk  = (lane & 7) ^ (row & 7);
        g2l16(wp1t + (size_t)row * 64 + kk * 8, &Bs[0][w * 32 + c * 8][0]);
    }
    __syncthreads();

    for (int ko = 0; ko < NOFF; ko++) {
        int cur = ko & 1;
        if (ko + 1 < NOFF) {
            int nxt = (ko + 1) & 1;
            #pragma unroll
            for (int c = 0; c < 4; c++) {
                int row = sr + c * 8;
                int kk  = (lane & 7) ^ (row & 7);
                g2l16(wp1t + (size_t)(ko + 1) * 8192 + (size_t)row * 64 + kk * 8,
                      &Bs[nxt][w * 32 + c * 8][0]);
            }
        }
        int nb = nbr_s[arow][ko];
        const u16* ap = xf + (size_t)nb * CIN + quad * 8;
        s16x8 af0 = *(const s16x8*)(ap);
        s16x8 af1 = *(const s16x8*)(ap + 32);
        #pragma unroll
        for (int nt = 0; nt < 8; nt++) {
            int pc0 = quad ^ (l15 & 7);
            int pc1 = (4 + quad) ^ (l15 & 7);
            s16x8 bf0 = *(const s16x8*)&Bs[cur][nt * 16 + l15][pc0 * 8];
            s16x8 bf1 = *(const s16x8*)&Bs[cur][nt * 16 + l15][pc1 * 8];
            oacc[nt] = __builtin_amdgcn_mfma_f32_16x16x32_bf16(af0, bf0, oacc[nt], 0, 0, 0);
            oacc[nt] = __builtin_amdgcn_mfma_f32_16x16x32_bf16(af1, bf1, oacc[nt], 0, 0, 0);
        }
        __syncthreads();
    }

    u16* xq = &Bs[0][0][0];   // [64][136] view
    #pragma unroll
    for (int nt = 0; nt < 8; nt++)
        #pragma unroll
        for (int r = 0; r < 4; r++) {
            int row = w * 16 + quad * 4 + r;
            int col = nt * 16 + l15;
            xdec[(size_t)(base + row) * NF + col] = oacc[nt][r];
            xq[row * 136 + col] = f2b(oacc[nt][r]);
        }

    s16x8 aq[4];
    #pragma unroll
    for (int ks = 0; ks < 4; ks++)
        aq[ks] = *(const s16x8*)&xq[(w * 16 + l15) * 136 + ks * 32 + quad * 8];

    #pragma unroll
    for (int nt = 0; nt < 8; nt++) {
        f32x4 acc = (f32x4)0.f;
        const u16* Wp = wqT + (size_t)(nt * 16 + l15) * NF + quad * 8;
        #pragma unroll
        for (int ks = 0; ks < 4; ks++) {
            s16x8 bf = *(const s16x8*)(Wp + ks * 32);
            acc = __builtin_amdgcn_mfma_f32_16x16x32_bf16(aq[ks], bf, acc, 0, 0, 0);
        }
        #pragma unroll
        for (int r = 0; r < 4; r++)
            qbuf[(size_t)(base + w * 16 + quad * 4 + r) * NF + nt * 16 + l15] = f2b(acc[r]);
    }
}

// ---------------------------------------------------------------------------
// Kernel 3: MFMA flash attention — R9 structure (128 q/block, dbuf K+V,
// 1 barrier/tile), softmax via __expf (v_exp_f32 fast path; R7-validated).
// ---------------------------------------------------------------------------
__global__ __launch_bounds__(256) void attn_mfma_kernel(
    const u16* __restrict__ Q, const u16* __restrict__ K,
    const u16* __restrict__ Vt, u16* __restrict__ Opart,
    float* __restrict__ lpart)
{
    __shared__ u16 Ks[2][64][128];
    __shared__ u16 Vs[2][128][64];
    __shared__ u16 Ps[4][16][72];

    const int t    = threadIdx.x;
    const int b    = blockIdx.y;
    const int q0   = blockIdx.x * 128;
    const int sp   = blockIdx.z;
    const int w    = t >> 6;
    const int lane = t & 63;
    const int quad = lane >> 4;
    const int l15  = lane & 15;

    const u16* Kb  = K  + (size_t)b * SKV * NF;
    const u16* Vtb = Vt + (size_t)b * NF * SKV;

    s16x8 qf[2][4];
    #pragma unroll
    for (int g = 0; g < 2; g++) {
        const u16* Qp = Q + ((size_t)(b * SQ + q0 + w * 32 + g * 16 + l15)) * NF + quad * 8;
        #pragma unroll
        for (int ks = 0; ks < 4; ks++) qf[g][ks] = *(const s16x8*)(Qp + ks * 32);
    }

    f32x4 oacc[2][8];
    #pragma unroll
    for (int g = 0; g < 2; g++)
        #pragma unroll
        for (int n = 0; n < 8; n++) oacc[g][n] = (f32x4)0.f;
    float lrow[2] = {0.f, 0.f};

    const int kvbase = sp * KV_PER_SPLIT;
    const int krow = w * 16 + (lane >> 4);
    const int vrow = w * 32 + (lane >> 3);

    #pragma unroll
    for (int c = 0; c < 4; c++) {
        int row = krow + c * 4;
        int k8  = (lane & 15) ^ (row & 15);
        g2l16(Kb + (size_t)(kvbase + row) * NF + k8 * 8, &Ks[0][w * 16 + c * 4][0]);
    }
    #pragma unroll
    for (int c = 0; c < 4; c++) {
        int row = vrow + c * 8;
        int k8  = (lane & 7) ^ (row & 7);
        g2l16(Vtb + (size_t)row * SKV + kvbase + k8 * 8, &Vs[0][w * 32 + c * 8][0]);
    }

    for (int tile = 0; tile < TILES_PER_SPLIT; tile++) {
        const int cur = tile & 1;
        __syncthreads();
        if (tile + 1 < TILES_PER_SPLIT) {
            const int nxt = (tile + 1) & 1;
            int kvn = kvbase + (tile + 1) * 64;
            #pragma unroll
            for (int c = 0; c < 4; c++) {
                int row = krow + c * 4;
                int k8  = (lane & 15) ^ (row & 15);
                g2l16(Kb + (size_t)(kvn + row) * NF + k8 * 8, &Ks[nxt][w * 16 + c * 4][0]);
            }
            #pragma unroll
            for (int c = 0; c < 4; c++) {
                int row = vrow + c * 8;
                int k8  = (lane & 7) ^ (row & 7);
                g2l16(Vtb + (size_t)row * SKV + kvn + k8 * 8, &Vs[nxt][w * 32 + c * 8][0]);
            }
        }

        f32x4 sacc[2][4];
        #pragma unroll
        for (int c = 0; c < 4; c++) {
            sacc[0][c] = (f32x4)0.f;
            sacc[1][c] = (f32x4)0.f;
            #pragma unroll
            for (int ks = 0; ks < 4; ks++) {
                int p = (ks * 4 + quad) ^ l15;
                s16x8 ka = *(const s16x8*)&Ks[cur][c * 16 + l15][p * 8];
                sacc[0][c] = __builtin_amdgcn_mfma_f32_16x16x32_bf16(ka, qf[0][ks], sacc[0][c], 0, 0, 0);
                sacc[1][c] = __builtin_amdgcn_mfma_f32_16x16x32_bf16(ka, qf[1][ks], sacc[1][c], 0, 0, 0);
            }
        }

        s16x8 pb[2][2];
        #pragma unroll
        for (int g = 0; g < 2; g++) {
            float rs = 0.f;
            float pv[4][4];
            #pragma unroll
            for (int c = 0; c < 4; c++)
                #pragma unroll
                for (int r = 0; r < 4; r++) {
                    float p = __expf(sacc[g][c][r] - SOFTMAX_SHIFT);
                    pv[c][r] = p;
                    rs += p;
                }
            rs += __shfl_xor(rs, 16);
            rs += __shfl_xor(rs, 32);
            lrow[g] += rs;
            #pragma unroll
            for (int c = 0; c < 4; c++) {
                uint2 pk;
                pk.x = pk2bf(pv[c][0], pv[c][1]);
                pk.y = pk2bf(pv[c][2], pv[c][3]);
                *(uint2*)&Ps[w][l15][c * 16 + quad * 4] = pk;
            }
            pb[g][0] = *(const s16x8*)&Ps[w][l15][quad * 8];
            pb[g][1] = *(const s16x8*)&Ps[w][l15][32 + quad * 8];
        }

        #pragma unroll
        for (int mt = 0; mt < 8; mt++) {
            int p0 = quad ^ (l15 & 7);
            int p1 = (4 + quad) ^ (l15 & 7);
            s16x8 va0 = *(const s16x8*)&Vs[cur][mt * 16 + l15][p0 * 8];
            s16x8 va1 = *(const s16x8*)&Vs[cur][mt * 16 + l15][p1 * 8];
            oacc[0][mt] = __builtin_amdgcn_mfma_f32_16x16x32_bf16(va0, pb[0][0], oacc[0][mt], 0, 0, 0);
            oacc[0][mt] = __builtin_amdgcn_mfma_f32_16x16x32_bf16(va1, pb[0][1], oacc[0][mt], 0, 0, 0);
            oacc[1][mt] = __builtin_amdgcn_mfma_f32_16x16x32_bf16(va0, pb[1][0], oacc[1][mt], 0, 0, 0);
            oacc[1][mt] = __builtin_amdgcn_mfma_f32_16x16x32_bf16(va1, pb[1][1], oacc[1][mt], 0, 0, 0);
        }
    }

    #pragma unroll
    for (int g = 0; g < 2; g++) {
        int grow = b * SQ + q0 + w * 32 + g * 16 + l15;
        u16* Ob = Opart + (size_t)sp * NQ * NF + (size_t)grow * NF;
        #pragma unroll
        for (int mt = 0; mt < 8; mt++) {
            uint2 ov;
            ov.x = pk2bf(oacc[g][mt][0], oacc[g][mt][1]);
            ov.y = pk2bf(oacc[g][mt][2], oacc[g][mt][3]);
            *(uint2*)(Ob + mt * 16 + quad * 4) = ov;
        }
        if (quad == 0) lpart[sp * NQ + grow] = lrow[g];
    }
}

// ---------------------------------------------------------------------------
// Kernel 4: fused merge + trans-GEMM + BN stats — R9 version (1-split).
// ---------------------------------------------------------------------------
__global__ __launch_bounds__(256) void tgemm_fused_kernel(
    const u16* __restrict__ Opart, const float* __restrict__ lpart,
    const u16* __restrict__ WT, float* __restrict__ C, float* __restrict__ stats)
{
    const int t    = threadIdx.x;
    const int w    = t >> 6;
    const int lane = t & 63;
    const int quad = lane >> 4;
    const int l15  = lane & 15;
    const int m0   = blockIdx.x * 64 + w * 16;
    const int row  = m0 + l15;

    float L = 0.f;
    #pragma unroll
    for (int s = 0; s < SPLIT; s++) L += lpart[s * NQ + row];
    float invL = 1.f / L;

    s16x8 af[4];
    #pragma unroll
    for (int ks = 0; ks < 4; ks++) {
        float sum[8] = {0.f, 0.f, 0.f, 0.f, 0.f, 0.f, 0.f, 0.f};
        #pragma unroll
        for (int s = 0; s < SPLIT; s++) {
            const u16* p = Opart + (size_t)s * NQ * NF + (size_t)row * NF + ks * 32 + quad * 8;
            ushort4 u0 = *(const ushort4*)p;
            ushort4 u1 = *(const ushort4*)(p + 4);
            sum[0] += b2f(u0.x); sum[1] += b2f(u0.y);
            sum[2] += b2f(u0.z); sum[3] += b2f(u0.w);
            sum[4] += b2f(u1.x); sum[5] += b2f(u1.y);
            sum[6] += b2f(u1.z); sum[7] += b2f(u1.w);
        }
        union { u16 a[8]; s16x8 v; } pk;
        #pragma unroll
        for (int j = 0; j < 8; j++) pk.a[j] = f2b(sum[j] * invL);
        af[ks] = pk.v;
    }

    f32x4 oacc[8];
    #pragma unroll
    for (int nt = 0; nt < 8; nt++) {
        oacc[nt] = (f32x4)0.f;
        const u16* Wp = WT + (size_t)(nt * 16 + l15) * NF + quad * 8;
        #pragma unroll
        for (int ks = 0; ks < 4; ks++) {
            s16x8 bf = *(const s16x8*)(Wp + ks * 32);
            oacc[nt] = __builtin_amdgcn_mfma_f32_16x16x32_bf16(af[ks], bf, oacc[nt], 0, 0, 0);
        }
    }

    float s[8], sq[8];
    #pragma unroll
    for (int nt = 0; nt < 8; nt++) {
        s[nt] = 0.f; sq[nt] = 0.f;
        #pragma unroll
        for (int r = 0; r < 4; r++) {
            float v = oacc[nt][r];
            C[(size_t)(m0 + quad * 4 + r) * NF + nt * 16 + l15] = v;
            s[nt] += v; sq[nt] += v * v;
        }
    }
    #pragma unroll
    for (int nt = 0; nt < 8; nt++) {
        s[nt]  += __shfl_xor(s[nt], 16);  s[nt]  += __shfl_xor(s[nt], 32);
        sq[nt] += __shfl_xor(sq[nt], 16); sq[nt] += __shfl_xor(sq[nt], 32);
    }
    __shared__ float red[2][4][128];
    if (quad == 0) {
        #pragma unroll
        for (int nt = 0; nt < 8; nt++) {
            red[0][w][nt * 16 + l15] = s[nt];
            red[1][w][nt * 16 + l15] = sq[nt];
        }
    }
    __syncthreads();
    if (t < 128) {
        float a = red[0][0][t] + red[0][1][t] + red[0][2][t] + red[0][3][t];
        atomicAdd(&stats[t], a);
    } else if (t < 256) {
        int f = t - 128;
        float a = red[1][0][f] + red[1][1][f] + red[1][2][f] + red[1][3][f];
        atomicAdd(&stats[128 + f], a);
    }
}

// ---------------------------------------------------------------------------
// Kernel 5: out = x_dec + BN(t). Unchanged.
// ---------------------------------------------------------------------------
__global__ __launch_bounds__(256) void bn_finalize(
    const float* __restrict__ tbuf, const float* __restrict__ xdec,
    const float* __restrict__ stats, const float* __restrict__ gamma,
    const float* __restrict__ beta, float* __restrict__ out)
{
    const int g = blockIdx.x * 256 + threadIdx.x;
    const int e = g * 4;
    const int f = e & (NF - 1);
    const float invN = 1.0f / (float)NQ;
    float4 tv = *(const float4*)(tbuf + e);
    float4 xv = *(const float4*)(xdec + e);
    float o[4], tt[4] = {tv.x, tv.y, tv.z, tv.w}, xx[4] = {xv.x, xv.y, xv.z, xv.w};
    #pragma unroll
    for (int u = 0; u < 4; u++) {
        float sum  = stats[f + u];
        float sumq = stats[128 + f + u];
        float mean = sum * invN;
        float var  = sumq * invN - mean * mean;
        float sc   = rsqrtf(var + BN_EPS) * gamma[f + u];
        o[u] = xx[u] + (tt[u] - mean) * sc + beta[f + u];
    }
    float4 ov = make_float4(o[0], o[1], o[2], o[3]);
    *(float4*)(out + e) = ov;
}

// ---------------------------------------------------------------------------
extern "C" void kernel_launch(void* const* d_in, const int* in_sizes, int n_in,
                              void* d_out, int out_size, void* d_ws, size_t ws_size,
                              hipStream_t stream) {
    const float* xdec_feat = (const float*)d_in[0];
    const float* xenc_feat = (const float*)d_in[1];
    const int*   nbr       = (const int*)d_in[2];
    const float* Wp1       = (const float*)d_in[3];
    const float* Wq        = (const float*)d_in[4];
    const float* Wk        = (const float*)d_in[5];
    const float* Wv        = (const float*)d_in[6];
    const float* Wt        = (const float*)d_in[7];
    const float* gamma     = (const float*)d_in[8];
    const float* beta      = (const float*)d_in[9];
    float* out = (float*)d_out;

    char* wsb = (char*)d_ws;
    const size_t MB = 1024 * 1024;
    float* xdec   = (float*)(wsb + 0);            //  0..8M   fp32 NQ*NF
    u16*   qbuf   = (u16*)  (wsb + 8 * MB);       //  8..12M  bf16 NQ*NF
    u16*   kbuf   = (u16*)  (wsb + 12 * MB);      // 12..20M  bf16 NKV*NF
    u16*   vt     = (u16*)  (wsb + 20 * MB);      // 20..28M  bf16 NKV*NF (V^T)
    u16*   opart  = (u16*)  (wsb + 28 * MB);      // 28..44M  bf16 SPLIT*NQ*NF
    u16*   xf_bf  = (u16*)  (wsb + 44 * MB);      // 2M
    u16*   wp1t   = (u16*)  (wsb + 46 * MB);      // ~432K
    u16*   wqT    = (u16*)  (wsb + 46 * MB + 512 * 1024);
    u16*   wkT    = (u16*)  (wsb + 46 * MB + 512 * 1024 + 32768);
    u16*   wvT    = (u16*)  (wsb + 46 * MB + 512 * 1024 + 49152);
    u16*   wtT    = (u16*)  (wsb + 46 * MB + 512 * 1024 + 65536);
    float* lpart  = (float*)(wsb + 47 * MB);
    float* stats  = (float*)(wsb + 47 * MB + 512 * 1024);
    float* tbuf   = (float*)(wsb + 12 * MB);      // reuses kbuf (dead after attn)

    prep_kernel<<<1289, 256, 0, stream>>>(
        xdec_feat, Wp1, Wq, Wk, Wv, Wt,
        xf_bf, wp1t, wqT, wkT, wvT, wtT, stats);
    main_fused_kernel<<<768, 256, 0, stream>>>(
        xenc_feat, xf_bf, nbr, wp1t, wqT, wkT, wvT,
        kbuf, vt, xdec, qbuf);
    attn_mfma_kernel<<<dim3(SQ / 128, BATCH, SPLIT), 256, 0, stream>>>(
        qbuf, kbuf, vt, opart, lpart);
    tgemm_fused_kernel<<<NQ / 64, 256, 0, stream>>>(opart, lpart, wtT, tbuf, stats);
    bn_finalize<<<(NQ * NF) / 1024, 256, 0, stream>>>(tbuf, xdec, stats, gamma, beta, out);
}